// Round 10
// baseline (154.037 us; speedup 1.0000x reference)
//
#include <hip/hip_runtime.h>

#define DD 256   // feature dim
#define N1 512
#define N2 512
#define BB 4

// Packed fp32 via <2 x float> vector IR -> v_pk_*_f32 (R5: never hand-write
// VOP3P inline asm).
typedef float f2 __attribute__((ext_vector_type(2)));

// ---------------------------------------------------------------------------
// Kernel 1: projection GEMMs — exact R7 version (best measured).
// 32(m) x 64(n) tile / 256 threads / 2x4 register blocking, K-chunks of 32,
// register-prefetch double buffering. 512 blocks = 2 blocks/CU.
// ---------------------------------------------------------------------------
__global__ __launch_bounds__(256) void proj_kernel(
    const float* __restrict__ x, const float* __restrict__ y,
    const float* __restrict__ W1, const float* __restrict__ b1,
    float* __restrict__ xp, float* __restrict__ yp)
{
    const int which = blockIdx.z;
    const float* __restrict__ A  = which ? y : x;
    const float* __restrict__ Bw = W1 + which * DD * DD;
    float* __restrict__ outp = which ? yp : xp;

    __shared__ float As[32 * 36];   // As[k][m] (transposed), stride 36
    __shared__ float Bs[32 * 68];   // Bs[k][n], stride 68

    const int tid = threadIdx.x;
    const int tx = tid & 15, ty = tid >> 4;
    const int mBase = blockIdx.x * 32;
    const int nBase = blockIdx.y * 64;

    const float4* A4 = (const float4*)A;
    const float4* B4 = (const float4*)Bw;

    const int ar = tid >> 3;       // 0..31  A row (m)
    const int ac = tid & 7;        // 0..7   A float4 col (k/4)
    const int br = tid >> 4;       // 0..15  B k-row (and +16)
    const int bc = tid & 15;       // 0..15  B float4 col (n/4)

    float4 pa, pb0, pb1;
    pa  = A4[(mBase + ar) * 64 + ac];
    pb0 = B4[br * 64 + (nBase >> 2) + bc];
    pb1 = B4[(br + 16) * 64 + (nBase >> 2) + bc];

    float acc[2][4] = {};

    for (int kc = 0; kc < 8; ++kc) {
        __syncthreads();
        {
            float av[4] = {pa.x, pa.y, pa.z, pa.w};
            #pragma unroll
            for (int q = 0; q < 4; ++q) As[(ac * 4 + q) * 36 + ar] = av[q];
            *(float4*)&Bs[br * 68 + bc * 4] = pb0;
            *(float4*)&Bs[(br + 16) * 68 + bc * 4] = pb1;
        }
        __syncthreads();
        if (kc < 7) {
            pa  = A4[(mBase + ar) * 64 + (kc + 1) * 8 + ac];
            pb0 = B4[((kc + 1) * 32 + br) * 64 + (nBase >> 2) + bc];
            pb1 = B4[((kc + 1) * 32 + br + 16) * 64 + (nBase >> 2) + bc];
        }
        #pragma unroll
        for (int k = 0; k < 32; ++k) {
            float2 a = *(const float2*)&As[k * 36 + ty * 2];
            float4 b = *(const float4*)&Bs[k * 68 + tx * 4];
            float av[2] = {a.x, a.y};
            float bv[4] = {b.x, b.y, b.z, b.w};
            #pragma unroll
            for (int i = 0; i < 2; ++i)
                #pragma unroll
                for (int j = 0; j < 4; ++j)
                    acc[i][j] = fmaf(av[i], bv[j], acc[i][j]);
        }
    }

    float4 bias = make_float4(0.f, 0.f, 0.f, 0.f);
    if (which == 0) bias = *((const float4*)b1 + (nBase >> 2) + tx);
    #pragma unroll
    for (int i = 0; i < 2; ++i) {
        float4 o;
        o.x = acc[i][0] + bias.x;
        o.y = acc[i][1] + bias.y;
        o.z = acc[i][2] + bias.z;
        o.w = acc[i][3] + bias.w;
        ((float4*)outp)[(mBase + ty * 2 + i) * (DD / 4) + (nBase >> 2) + tx] = o;
    }
}

// ---------------------------------------------------------------------------
// Packed tanh-form gelu pair (same math since R2, absmax 3.9e-3):
//   gelu(h) = h * (1 - 1/(exp2(h*(K1 + K2 h^2)) + 1))
// ---------------------------------------------------------------------------
__device__ __forceinline__ f2 gelu2(f2 h)
{
    f2 h2 = h * h;
    f2 t  = __builtin_elementwise_fma(h2, (f2)0.1029432f, (f2)2.3022083f);
    f2 z  = h * t;
    f2 e;
    e.x = __builtin_amdgcn_exp2f(z.x);
    e.y = __builtin_amdgcn_exp2f(z.y);
    f2 a = e + 1.0f;
    f2 r;
    r.x = __builtin_amdgcn_rcpf(a.x);
    r.y = __builtin_amdgcn_rcpf(a.y);
    return __builtin_elementwise_fma(-h, r, h);   // h - h*r = h*sigmoid(z)
}

// ---------------------------------------------------------------------------
// Kernel 2 (R10 rewrite): o[b,n,m] = sum_d gelu(xp[b,n,d]+yp[b,m,d])*W2[d]+b2
// BARRIER-FREE main loop. Block = 32n x 32m, 4 waves, 4 blocks/CU (LDS 32 KB
// exactly). Per lane: m = lane&31, 4 consecutive n (wave*8 + half*4).
//  - y panel transposed into LDS ONCE (yt[d][m]); main-loop y reads are
//    same-address broadcasts across lane halves (conflict-free b32).
//  - x streamed global->register with ping-pong prefetch (the one pattern
//    the compiler has never rolled back, R2-R9).
//  - W2 prefetched one group ahead (uniform -> s_load).
// After the single barrier the 16 waves/CU never re-sync: trans bursts and
// load waits of different waves interleave instead of convoying.
// ---------------------------------------------------------------------------
__global__ __launch_bounds__(256, 4) void cross_kernel(
    const float* __restrict__ xp, const float* __restrict__ yp,
    const float* __restrict__ W2, const float* __restrict__ b2,
    float* __restrict__ o)
{
    __shared__ float yt[256 * 32];     // yt[d][m], 32 KB, bank(d,m)=m

    const int tid   = threadIdx.x;
    const int b     = blockIdx.z;
    const int mBase = blockIdx.x * 32;
    const int nBase = blockIdx.y * 32;

    // ---- transpose stage: yp[mBase..+32)[0..256) -> yt[d][m] (once)
    {
        const int m    = tid & 31;
        const int dblk = tid >> 5;     // 0..7, 32 d-values each
        const float4* src = (const float4*)yp
                          + ((size_t)(b * N2 + mBase + m)) * 64 + dblk * 8;
        #pragma unroll
        for (int k = 0; k < 8; ++k) {
            float4 v = src[k];
            int d0 = dblk * 32 + k * 4;
            // lanes 0-31 vs 32-63: same bank m, different addr = 2-way (free)
            yt[(d0 + 0) * 32 + m] = v.x;
            yt[(d0 + 1) * 32 + m] = v.y;
            yt[(d0 + 2) * 32 + m] = v.z;
            yt[(d0 + 3) * 32 + m] = v.w;
        }
    }
    __syncthreads();   // the only barrier

    const int wave = tid >> 6;           // 0..3
    const int lane = tid & 63;
    const int m    = lane & 31;
    const int half = lane >> 5;          // 0/1
    const int n0   = nBase + wave * 8 + half * 4;   // this lane's 4 n-rows

    const float4* x4 = (const float4*)(xp + ((size_t)(b * N1 + n0)) * DD);
    // x4[j*64 + g] = xp[n0+j][4g .. 4g+3]
    const float4* __restrict__ W2v = (const float4*)W2;

    f2 acc[4] = {};
    float4 xa[4], xb[4];
    #pragma unroll
    for (int j = 0; j < 4; ++j) xa[j] = x4[j * 64 + 0];
    float4 wcur = W2v[0];

    for (int g = 0; g < 64; g += 2) {
        // ---- even group g: compute from xa, prefetch g+1 into xb
        #pragma unroll
        for (int j = 0; j < 4; ++j) xb[j] = x4[j * 64 + g + 1];
        float4 wnxt = W2v[g + 1];
        {
            const int d0 = g * 4;
            f2 y01 = { yt[(d0 + 0) * 32 + m], yt[(d0 + 1) * 32 + m] };
            f2 y23 = { yt[(d0 + 2) * 32 + m], yt[(d0 + 3) * 32 + m] };
            f2 wlo = {wcur.x, wcur.y};
            f2 whi = {wcur.z, wcur.w};
            #pragma unroll
            for (int j = 0; j < 4; ++j) {
                f2 xlo = {xa[j].x, xa[j].y};
                f2 xhi = {xa[j].z, xa[j].w};
                f2 glo = gelu2(xlo + y01);
                acc[j] = __builtin_elementwise_fma(glo, wlo, acc[j]);
                f2 ghi = gelu2(xhi + y23);
                acc[j] = __builtin_elementwise_fma(ghi, whi, acc[j]);
            }
        }
        // ---- odd group g+1: compute from xb, prefetch g+2 into xa
        if (g < 62) {
            #pragma unroll
            for (int j = 0; j < 4; ++j) xa[j] = x4[j * 64 + g + 2];
        }
        float4 wnn = (g < 62) ? W2v[g + 2] : wnxt;
        {
            const int d0 = (g + 1) * 4;
            f2 y01 = { yt[(d0 + 0) * 32 + m], yt[(d0 + 1) * 32 + m] };
            f2 y23 = { yt[(d0 + 2) * 32 + m], yt[(d0 + 3) * 32 + m] };
            f2 wlo = {wnxt.x, wnxt.y};
            f2 whi = {wnxt.z, wnxt.w};
            #pragma unroll
            for (int j = 0; j < 4; ++j) {
                f2 xlo = {xb[j].x, xb[j].y};
                f2 xhi = {xb[j].z, xb[j].w};
                f2 glo = gelu2(xlo + y01);
                acc[j] = __builtin_elementwise_fma(glo, wlo, acc[j]);
                f2 ghi = gelu2(xhi + y23);
                acc[j] = __builtin_elementwise_fma(ghi, whi, acc[j]);
            }
        }
        wcur = wnn;
    }

    const float bias2 = b2[0];
    float* ob = o + (size_t)b * N1 * N2;
    #pragma unroll
    for (int j = 0; j < 4; ++j) {
        // half-wave writes 128 B contiguous per n-row: coalesced
        ob[(size_t)(n0 + j) * N2 + mBase + m] = acc[j].x + acc[j].y + bias2;
    }
}

extern "C" void kernel_launch(void* const* d_in, const int* in_sizes, int n_in,
                              void* d_out, int out_size, void* d_ws, size_t ws_size,
                              hipStream_t stream)
{
    const float* x  = (const float*)d_in[0];
    const float* y  = (const float*)d_in[1];
    const float* W1 = (const float*)d_in[2];
    const float* b1 = (const float*)d_in[3];
    const float* W2 = (const float*)d_in[4];
    const float* b2 = (const float*)d_in[5];
    float* o  = (float*)d_out;
    float* xp = (float*)d_ws;                 // 2048*256 floats = 2 MB
    float* yp = xp + (BB * N1) * DD;          // next 2 MB

    dim3 g1(64, 4, 2);               // (M/32, N/64, which) = 512 blocks
    proj_kernel<<<g1, 256, 0, stream>>>(x, y, W1, b1, xp, yp);

    dim3 g2(N2 / 32, N1 / 32, BB);   // 16 x 16 x 4 = 1024 four-wave blocks
    cross_kernel<<<g2, 256, 0, stream>>>(xp, yp, W2, b2, o);
}

// Round 11
// 153.751 us; speedup vs baseline: 1.0019x; 1.0019x over previous
//
#include <hip/hip_runtime.h>

#define DD 256   // feature dim
#define N1 512
#define N2 512
#define BB 4

// Packed fp32 via <2 x float> vector IR -> v_pk_*_f32 (R5: never hand-write
// VOP3P inline asm).
typedef float f2 __attribute__((ext_vector_type(2)));

// ---------------------------------------------------------------------------
// Kernel 1: projection GEMMs — exact R7 version (best measured).
// 32(m) x 64(n) tile / 256 threads / 2x4 register blocking, K-chunks of 32,
// register-prefetch double buffering. 512 blocks = 2 blocks/CU.
// ---------------------------------------------------------------------------
__global__ __launch_bounds__(256) void proj_kernel(
    const float* __restrict__ x, const float* __restrict__ y,
    const float* __restrict__ W1, const float* __restrict__ b1,
    float* __restrict__ xp, float* __restrict__ yp)
{
    const int which = blockIdx.z;
    const float* __restrict__ A  = which ? y : x;
    const float* __restrict__ Bw = W1 + which * DD * DD;
    float* __restrict__ outp = which ? yp : xp;

    __shared__ float As[32 * 36];   // As[k][m] (transposed), stride 36
    __shared__ float Bs[32 * 68];   // Bs[k][n], stride 68

    const int tid = threadIdx.x;
    const int tx = tid & 15, ty = tid >> 4;
    const int mBase = blockIdx.x * 32;
    const int nBase = blockIdx.y * 64;

    const float4* A4 = (const float4*)A;
    const float4* B4 = (const float4*)Bw;

    const int ar = tid >> 3;       // 0..31  A row (m)
    const int ac = tid & 7;        // 0..7   A float4 col (k/4)
    const int br = tid >> 4;       // 0..15  B k-row (and +16)
    const int bc = tid & 15;       // 0..15  B float4 col (n/4)

    float4 pa, pb0, pb1;
    pa  = A4[(mBase + ar) * 64 + ac];
    pb0 = B4[br * 64 + (nBase >> 2) + bc];
    pb1 = B4[(br + 16) * 64 + (nBase >> 2) + bc];

    float acc[2][4] = {};

    for (int kc = 0; kc < 8; ++kc) {
        __syncthreads();
        {
            float av[4] = {pa.x, pa.y, pa.z, pa.w};
            #pragma unroll
            for (int q = 0; q < 4; ++q) As[(ac * 4 + q) * 36 + ar] = av[q];
            *(float4*)&Bs[br * 68 + bc * 4] = pb0;
            *(float4*)&Bs[(br + 16) * 68 + bc * 4] = pb1;
        }
        __syncthreads();
        if (kc < 7) {
            pa  = A4[(mBase + ar) * 64 + (kc + 1) * 8 + ac];
            pb0 = B4[((kc + 1) * 32 + br) * 64 + (nBase >> 2) + bc];
            pb1 = B4[((kc + 1) * 32 + br + 16) * 64 + (nBase >> 2) + bc];
        }
        #pragma unroll
        for (int k = 0; k < 32; ++k) {
            float2 a = *(const float2*)&As[k * 36 + ty * 2];
            float4 b = *(const float4*)&Bs[k * 68 + tx * 4];
            float av[2] = {a.x, a.y};
            float bv[4] = {b.x, b.y, b.z, b.w};
            #pragma unroll
            for (int i = 0; i < 2; ++i)
                #pragma unroll
                for (int j = 0; j < 4; ++j)
                    acc[i][j] = fmaf(av[i], bv[j], acc[i][j]);
        }
    }

    float4 bias = make_float4(0.f, 0.f, 0.f, 0.f);
    if (which == 0) bias = *((const float4*)b1 + (nBase >> 2) + tx);
    #pragma unroll
    for (int i = 0; i < 2; ++i) {
        float4 o;
        o.x = acc[i][0] + bias.x;
        o.y = acc[i][1] + bias.y;
        o.z = acc[i][2] + bias.z;
        o.w = acc[i][3] + bias.w;
        ((float4*)outp)[(mBase + ty * 2 + i) * (DD / 4) + (nBase >> 2) + tx] = o;
    }
}

// ---------------------------------------------------------------------------
// Packed tanh-form gelu pair with ONE transcendental per element:
//   gelu(h) = h * (1 - 1/(exp2(h*(K1 + K2 h^2)) + 1))
// v_rcp replaced by magic-seed (0x7EF311C3 - bits, ~5% rel err) + 2 packed
// Newton iterations -> rel err ~7e-6 (absmax unchanged vs v_rcp).
// Trans ops/elem: 2 -> 1 (exp2 only). If trans is the bottleneck pipe,
// busy halves; the added 2 int-subs + 4 pk ops ride the idle VALU slots.
// ---------------------------------------------------------------------------
__device__ __forceinline__ f2 gelu2(f2 h)
{
    f2 h2 = h * h;
    f2 t  = __builtin_elementwise_fma(h2, (f2)0.1029432f, (f2)2.3022083f);
    f2 z  = h * t;
    f2 e;
    e.x = __builtin_amdgcn_exp2f(z.x);
    e.y = __builtin_amdgcn_exp2f(z.y);
    f2 a = e + 1.0f;                 // a in [1, ~1000]: normal, positive
    f2 r;
    r.x = __int_as_float(0x7EF311C3 - __float_as_int(a.x));
    r.y = __int_as_float(0x7EF311C3 - __float_as_int(a.y));
    f2 w = __builtin_elementwise_fma(-a, r, (f2)2.0f);   // 2 - a*r
    r = r * w;
    w = __builtin_elementwise_fma(-a, r, (f2)2.0f);
    r = r * w;                        // 1/a to ~7e-6 rel
    return __builtin_elementwise_fma(-h, r, h);   // h - h*r = h*sigmoid(z)
}

// ---------------------------------------------------------------------------
// Kernel 2: o[b,n,m] = sum_d gelu(xp[b,n,d] + yp[b,m,d]) * W2[d] + b2
// Exact R8 structure (best measured cross: 74.2 us): 32x32 tile / 256-thread
// (4-wave) block / 2x2 outputs/thread; W2 chunk preloaded to SGPRs per kc;
// depth-1 LDS read pipeline; register-prefetched global staging.
// Stride-68 LDS rows conflict-free (xr 16-lane broadcast, yr 2-way = free).
// ---------------------------------------------------------------------------
__global__ __launch_bounds__(256, 4) void cross_kernel(
    const float* __restrict__ xp, const float* __restrict__ yp,
    const float* __restrict__ W2, const float* __restrict__ b2,
    float* __restrict__ o)
{
    __shared__ float xs[32 * 68];
    __shared__ float ys[32 * 68];

    const int tid   = threadIdx.x;
    const int b     = blockIdx.z;
    const int mBase = blockIdx.x * 32;
    const int nBase = blockIdx.y * 32;
    const int tx = tid & 15;       // m sub-index (cols tx, tx+16)
    const int ty = tid >> 4;       // n sub-index (rows ty, ty+16)

    const float4* xp4 = (const float4*)xp + (b * N1 + nBase) * (DD / 4);
    const float4* yp4 = (const float4*)yp + (b * N2 + mBase) * (DD / 4);
    const float4* __restrict__ W2v = (const float4*)W2;

    const int srow = tid >> 4;          // 0..15
    const int sc4  = tid & 15;          // float4 col within chunk

    float4 px[2], py[2];
    px[0] = xp4[srow * 64 + sc4];
    px[1] = xp4[(srow + 16) * 64 + sc4];
    py[0] = yp4[srow * 64 + sc4];
    py[1] = yp4[(srow + 16) * 64 + sc4];

    f2 acc[2][2] = {};

    for (int kc = 0; kc < 4; ++kc) {
        __syncthreads();
        *(float4*)&xs[srow * 68 + sc4 * 4]        = px[0];
        *(float4*)&xs[(srow + 16) * 68 + sc4 * 4] = px[1];
        *(float4*)&ys[srow * 68 + sc4 * 4]        = py[0];
        *(float4*)&ys[(srow + 16) * 68 + sc4 * 4] = py[1];
        __syncthreads();
        if (kc < 3) {
            px[0] = xp4[srow * 64 + (kc + 1) * 16 + sc4];
            px[1] = xp4[(srow + 16) * 64 + (kc + 1) * 16 + sc4];
            py[0] = yp4[srow * 64 + (kc + 1) * 16 + sc4];
            py[1] = yp4[(srow + 16) * 64 + (kc + 1) * 16 + sc4];
        }

        // W2 chunk -> SGPRs (uniform loads), one burst per kc
        float4 wreg[16];
        #pragma unroll
        for (int c4 = 0; c4 < 16; ++c4) wreg[c4] = W2v[kc * 16 + c4];

        // depth-1 software pipeline on LDS reads
        float4 xr[2][2], yr[2][2];
        #pragma unroll
        for (int i = 0; i < 2; ++i) {
            xr[0][i] = *(const float4*)&xs[(ty + 16 * i) * 68];
            yr[0][i] = *(const float4*)&ys[(tx + 16 * i) * 68];
        }

        #pragma unroll
        for (int c4 = 0; c4 < 16; ++c4) {
            const int cur = c4 & 1, nxt = cur ^ 1;
            if (c4 < 15) {
                #pragma unroll
                for (int i = 0; i < 2; ++i) {
                    xr[nxt][i] = *(const float4*)&xs[(ty + 16 * i) * 68 + (c4 + 1) * 4];
                    yr[nxt][i] = *(const float4*)&ys[(tx + 16 * i) * 68 + (c4 + 1) * 4];
                }
            }
            float4 wv = wreg[c4];
            f2 wlo = {wv.x, wv.y};
            f2 whi = {wv.z, wv.w};
            #pragma unroll
            for (int i = 0; i < 2; ++i) {
                f2 xlo = {xr[cur][i].x, xr[cur][i].y};
                f2 xhi = {xr[cur][i].z, xr[cur][i].w};
                #pragma unroll
                for (int j = 0; j < 2; ++j) {
                    f2 ylo = {yr[cur][j].x, yr[cur][j].y};
                    f2 yhi = {yr[cur][j].z, yr[cur][j].w};
                    f2 glo = gelu2(xlo + ylo);
                    acc[i][j] = __builtin_elementwise_fma(glo, wlo, acc[i][j]);
                    f2 ghi = gelu2(xhi + yhi);
                    acc[i][j] = __builtin_elementwise_fma(ghi, whi, acc[i][j]);
                }
            }
        }
    }

    const float bias2 = b2[0];
    const size_t base = ((size_t)(b * N1 + nBase)) * N2 + mBase;
    #pragma unroll
    for (int i = 0; i < 2; ++i) {
        #pragma unroll
        for (int j = 0; j < 2; ++j) {
            o[base + (size_t)(ty + 16 * i) * N2 + (tx + 16 * j)] =
                acc[i][j].x + acc[i][j].y + bias2;
        }
    }
}

extern "C" void kernel_launch(void* const* d_in, const int* in_sizes, int n_in,
                              void* d_out, int out_size, void* d_ws, size_t ws_size,
                              hipStream_t stream)
{
    const float* x  = (const float*)d_in[0];
    const float* y  = (const float*)d_in[1];
    const float* W1 = (const float*)d_in[2];
    const float* b1 = (const float*)d_in[3];
    const float* W2 = (const float*)d_in[4];
    const float* b2 = (const float*)d_in[5];
    float* o  = (float*)d_out;
    float* xp = (float*)d_ws;                 // 2048*256 floats = 2 MB
    float* yp = xp + (BB * N1) * DD;          // next 2 MB

    dim3 g1(64, 4, 2);               // (M/32, N/64, which) = 512 blocks
    proj_kernel<<<g1, 256, 0, stream>>>(x, y, W1, b1, xp, yp);

    dim3 g2(N2 / 32, N1 / 32, BB);   // 16 x 16 x 4 = 1024 four-wave blocks
    cross_kernel<<<g2, 256, 0, stream>>>(xp, yp, W2, b2, o);
}

// Round 12
// 147.642 us; speedup vs baseline: 1.0433x; 1.0414x over previous
//
#include <hip/hip_runtime.h>

#define DD 256   // feature dim
#define N1 512
#define N2 512
#define BB 4

// Packed fp32 via <2 x float> vector IR -> v_pk_*_f32 (R5: never hand-write
// VOP3P inline asm).
typedef float f2 __attribute__((ext_vector_type(2)));

// ---------------------------------------------------------------------------
// Kernel 1: projection GEMMs — exact R7 version (best measured).
// 32(m) x 64(n) tile / 256 threads / 2x4 register blocking, K-chunks of 32,
// register-prefetch double buffering. 512 blocks = 2 blocks/CU.
// ---------------------------------------------------------------------------
__global__ __launch_bounds__(256) void proj_kernel(
    const float* __restrict__ x, const float* __restrict__ y,
    const float* __restrict__ W1, const float* __restrict__ b1,
    float* __restrict__ xp, float* __restrict__ yp)
{
    const int which = blockIdx.z;
    const float* __restrict__ A  = which ? y : x;
    const float* __restrict__ Bw = W1 + which * DD * DD;
    float* __restrict__ outp = which ? yp : xp;

    __shared__ float As[32 * 36];   // As[k][m] (transposed), stride 36
    __shared__ float Bs[32 * 68];   // Bs[k][n], stride 68

    const int tid = threadIdx.x;
    const int tx = tid & 15, ty = tid >> 4;
    const int mBase = blockIdx.x * 32;
    const int nBase = blockIdx.y * 64;

    const float4* A4 = (const float4*)A;
    const float4* B4 = (const float4*)Bw;

    const int ar = tid >> 3;       // 0..31  A row (m)
    const int ac = tid & 7;        // 0..7   A float4 col (k/4)
    const int br = tid >> 4;       // 0..15  B k-row (and +16)
    const int bc = tid & 15;       // 0..15  B float4 col (n/4)

    float4 pa, pb0, pb1;
    pa  = A4[(mBase + ar) * 64 + ac];
    pb0 = B4[br * 64 + (nBase >> 2) + bc];
    pb1 = B4[(br + 16) * 64 + (nBase >> 2) + bc];

    float acc[2][4] = {};

    for (int kc = 0; kc < 8; ++kc) {
        __syncthreads();
        {
            float av[4] = {pa.x, pa.y, pa.z, pa.w};
            #pragma unroll
            for (int q = 0; q < 4; ++q) As[(ac * 4 + q) * 36 + ar] = av[q];
            *(float4*)&Bs[br * 68 + bc * 4] = pb0;
            *(float4*)&Bs[(br + 16) * 68 + bc * 4] = pb1;
        }
        __syncthreads();
        if (kc < 7) {
            pa  = A4[(mBase + ar) * 64 + (kc + 1) * 8 + ac];
            pb0 = B4[((kc + 1) * 32 + br) * 64 + (nBase >> 2) + bc];
            pb1 = B4[((kc + 1) * 32 + br + 16) * 64 + (nBase >> 2) + bc];
        }
        #pragma unroll
        for (int k = 0; k < 32; ++k) {
            float2 a = *(const float2*)&As[k * 36 + ty * 2];
            float4 b = *(const float4*)&Bs[k * 68 + tx * 4];
            float av[2] = {a.x, a.y};
            float bv[4] = {b.x, b.y, b.z, b.w};
            #pragma unroll
            for (int i = 0; i < 2; ++i)
                #pragma unroll
                for (int j = 0; j < 4; ++j)
                    acc[i][j] = fmaf(av[i], bv[j], acc[i][j]);
        }
    }

    float4 bias = make_float4(0.f, 0.f, 0.f, 0.f);
    if (which == 0) bias = *((const float4*)b1 + (nBase >> 2) + tx);
    #pragma unroll
    for (int i = 0; i < 2; ++i) {
        float4 o;
        o.x = acc[i][0] + bias.x;
        o.y = acc[i][1] + bias.y;
        o.z = acc[i][2] + bias.z;
        o.w = acc[i][3] + bias.w;
        ((float4*)outp)[(mBase + ty * 2 + i) * (DD / 4) + (nBase >> 2) + tx] = o;
    }
}

// ---------------------------------------------------------------------------
// Packed tanh-form gelu pair (R8's exact math, absmax 3.9e-3):
//   gelu(h) = h * (1 - 1/(exp2(h*(K1 + K2 h^2)) + 1))
// v_rcp restored: R11 proved Newton replacement costs MORE issue cycles
// than the rcp itself (trans issue ~3 cy, not 16).
// ---------------------------------------------------------------------------
__device__ __forceinline__ f2 gelu2(f2 h)
{
    f2 h2 = h * h;
    f2 t  = __builtin_elementwise_fma(h2, (f2)0.1029432f, (f2)2.3022083f);
    f2 z  = h * t;
    f2 e;
    e.x = __builtin_amdgcn_exp2f(z.x);
    e.y = __builtin_amdgcn_exp2f(z.y);
    f2 a = e + 1.0f;
    f2 r;
    r.x = __builtin_amdgcn_rcpf(a.x);
    r.y = __builtin_amdgcn_rcpf(a.y);
    return __builtin_elementwise_fma(-h, r, h);   // h - h*r = h*sigmoid(z)
}

// ---------------------------------------------------------------------------
// Kernel 2: o[b,n,m] = sum_d gelu(xp[b,n,d] + yp[b,m,d]) * W2[d] + b2
// R12 geometry fix: 32(n) x 16(m) tile / 128-thread (2-wave) block.
// 2048 blocks = 8 blocks/CU x ~9.3 us — halves the ramp/tail quantum that
// kept R7-R11 (1024 x 18.5 us blocks, exactly 4/CU, zero slack) at ~23 us
// CU idle. Residency unchanged: 8 blocks x 2 waves = 16 waves/CU
// (LDS 13.1 KB x 8 = 105 KB).
// Inner loop identical to R8 (best busy): W2 chunk -> SGPRs per kc, depth-1
// LDS pipeline, register-prefetched staging. Stride-68 rows: xr and yr both
// 8-distinct-row x 8-lane-broadcast = conflict-free.
// ---------------------------------------------------------------------------
__global__ __launch_bounds__(128, 4) void cross_kernel(
    const float* __restrict__ xp, const float* __restrict__ yp,
    const float* __restrict__ W2, const float* __restrict__ b2,
    float* __restrict__ o)
{
    __shared__ float xs[32 * 68];
    __shared__ float ys[16 * 68];

    const int tid   = threadIdx.x;
    const int b     = blockIdx.z;
    const int mBase = blockIdx.x * 16;
    const int nBase = blockIdx.y * 32;
    const int tx = tid & 7;        // m sub (cols tx, tx+8)
    const int ty = tid >> 3;       // n sub (rows ty, ty+16)

    const float4* xp4 = (const float4*)xp + (b * N1 + nBase) * (DD / 4);
    const float4* yp4 = (const float4*)yp + (b * N2 + mBase) * (DD / 4);
    const float4* __restrict__ W2v = (const float4*)W2;

    // staging geometry: xs 32 rows x 16 f4 (4/thread), ys 16 x 16 (2/thread)
    const int srow = tid >> 4;          // 0..7
    const int sc4  = tid & 15;          // float4 col within chunk

    float4 px[4], py[2];
    #pragma unroll
    for (int t = 0; t < 4; ++t) px[t] = xp4[(srow + 8 * t) * 64 + sc4];
    #pragma unroll
    for (int t = 0; t < 2; ++t) py[t] = yp4[(srow + 8 * t) * 64 + sc4];

    f2 acc[2][2] = {};

    for (int kc = 0; kc < 4; ++kc) {
        __syncthreads();
        #pragma unroll
        for (int t = 0; t < 4; ++t)
            *(float4*)&xs[(srow + 8 * t) * 68 + sc4 * 4] = px[t];
        #pragma unroll
        for (int t = 0; t < 2; ++t)
            *(float4*)&ys[(srow + 8 * t) * 68 + sc4 * 4] = py[t];
        __syncthreads();
        if (kc < 3) {
            #pragma unroll
            for (int t = 0; t < 4; ++t)
                px[t] = xp4[(srow + 8 * t) * 64 + (kc + 1) * 16 + sc4];
            #pragma unroll
            for (int t = 0; t < 2; ++t)
                py[t] = yp4[(srow + 8 * t) * 64 + (kc + 1) * 16 + sc4];
        }

        // W2 chunk -> SGPRs (uniform loads), one burst per kc
        float4 wreg[16];
        #pragma unroll
        for (int c4 = 0; c4 < 16; ++c4) wreg[c4] = W2v[kc * 16 + c4];

        // depth-1 software pipeline on LDS reads
        float4 xr[2][2], yr[2][2];
        #pragma unroll
        for (int i = 0; i < 2; ++i) {
            xr[0][i] = *(const float4*)&xs[(ty + 16 * i) * 68];
            yr[0][i] = *(const float4*)&ys[(tx + 8 * i) * 68];
        }

        #pragma unroll
        for (int c4 = 0; c4 < 16; ++c4) {
            const int cur = c4 & 1, nxt = cur ^ 1;
            if (c4 < 15) {
                #pragma unroll
                for (int i = 0; i < 2; ++i) {
                    xr[nxt][i] = *(const float4*)&xs[(ty + 16 * i) * 68 + (c4 + 1) * 4];
                    yr[nxt][i] = *(const float4*)&ys[(tx + 8 * i) * 68 + (c4 + 1) * 4];
                }
            }
            float4 wv = wreg[c4];
            f2 wlo = {wv.x, wv.y};
            f2 whi = {wv.z, wv.w};
            #pragma unroll
            for (int i = 0; i < 2; ++i) {
                f2 xlo = {xr[cur][i].x, xr[cur][i].y};
                f2 xhi = {xr[cur][i].z, xr[cur][i].w};
                #pragma unroll
                for (int j = 0; j < 2; ++j) {
                    f2 ylo = {yr[cur][j].x, yr[cur][j].y};
                    f2 yhi = {yr[cur][j].z, yr[cur][j].w};
                    f2 glo = gelu2(xlo + ylo);
                    acc[i][j] = __builtin_elementwise_fma(glo, wlo, acc[i][j]);
                    f2 ghi = gelu2(xhi + yhi);
                    acc[i][j] = __builtin_elementwise_fma(ghi, whi, acc[i][j]);
                }
            }
        }
    }

    const float bias2 = b2[0];
    const size_t base = ((size_t)(b * N1 + nBase)) * N2 + mBase;
    #pragma unroll
    for (int i = 0; i < 2; ++i) {
        #pragma unroll
        for (int j = 0; j < 2; ++j) {
            o[base + (size_t)(ty + 16 * i) * N2 + (tx + 8 * j)] =
                acc[i][j].x + acc[i][j].y + bias2;
        }
    }
}

extern "C" void kernel_launch(void* const* d_in, const int* in_sizes, int n_in,
                              void* d_out, int out_size, void* d_ws, size_t ws_size,
                              hipStream_t stream)
{
    const float* x  = (const float*)d_in[0];
    const float* y  = (const float*)d_in[1];
    const float* W1 = (const float*)d_in[2];
    const float* b1 = (const float*)d_in[3];
    const float* W2 = (const float*)d_in[4];
    const float* b2 = (const float*)d_in[5];
    float* o  = (float*)d_out;
    float* xp = (float*)d_ws;                 // 2048*256 floats = 2 MB
    float* yp = xp + (BB * N1) * DD;          // next 2 MB

    dim3 g1(64, 4, 2);               // (M/32, N/64, which) = 512 blocks
    proj_kernel<<<g1, 256, 0, stream>>>(x, y, W1, b1, xp, yp);

    dim3 g2(N2 / 16, N1 / 32, BB);   // 32 x 16 x 4 = 2048 two-wave blocks
    cross_kernel<<<g2, 128, 0, stream>>>(xp, yp, W2, b2, o);
}